// Round 1
// baseline (379.958 us; speedup 1.0000x reference)
//
#include <hip/hip_runtime.h>
#include <hip/hip_bf16.h>
#include <float.h>

// Problem: N=1024, M=1024, D=512. All fp32.
// ws layout (floats): qp[1024*512] | kpT[512*1024] | vp[1024*512] | S[1024*1024]
// qp,kpT pre-scaled by 2*log2(e) so tanh(q+k) = 1 - 2*rcp(1+exp2(qp'+kpT')).
// Softmax is shift-invariant -> drop (bw + sum(Ww)) entirely.

#define NROWS 1024
#define DDIM  512
#define MDIM  1024

// ---------------- Projection GEMM: out = (x @ W.T + b) * scale ----------------
// x: [1024,512], W: [512,512] row-major (out_j = dot(x_i, W_j)), 64x64 tile.
__global__ __launch_bounds__(256) void proj_gemm(const float* __restrict__ x,
                                                 const float* __restrict__ W,
                                                 const float* __restrict__ bias,
                                                 float* __restrict__ out,
                                                 float scale, int transp)
{
    __shared__ float xs[64 * 65];
    __shared__ float wsm[64 * 65];
    const int t  = threadIdx.x;
    const int tx = t & 15;        // 16 col groups of 4
    const int ty = t >> 4;        // 16 row groups of 4
    const int i0 = blockIdx.y * 64;   // rows (N dim)
    const int j0 = blockIdx.x * 64;   // cols (D-out dim)

    float acc[4][4] = {};

    for (int k0 = 0; k0 < DDIM; k0 += 64) {
        __syncthreads();
#pragma unroll
        for (int i = 0; i < 16; ++i) {
            int idx = t + i * 256;
            int r = idx >> 6, c = idx & 63;
            xs[r * 65 + c]  = x[(size_t)(i0 + r) * DDIM + k0 + c];
            wsm[r * 65 + c] = W[(size_t)(j0 + r) * DDIM + k0 + c];
        }
        __syncthreads();
#pragma unroll
        for (int k = 0; k < 64; ++k) {
            float a[4], bb[4];
#pragma unroll
            for (int i = 0; i < 4; ++i) a[i]  = xs[(ty * 4 + i) * 65 + k];
#pragma unroll
            for (int j = 0; j < 4; ++j) bb[j] = wsm[(tx * 4 + j) * 65 + k];
#pragma unroll
            for (int i = 0; i < 4; ++i)
#pragma unroll
                for (int j = 0; j < 4; ++j)
                    acc[i][j] = fmaf(a[i], bb[j], acc[i][j]);
        }
    }

#pragma unroll
    for (int j = 0; j < 4; ++j) {
        float bv = bias[j0 + tx * 4 + j];
#pragma unroll
        for (int i = 0; i < 4; ++i) {
            float val = (acc[i][j] + bv) * scale;
            int row = i0 + ty * 4 + i;
            int col = j0 + tx * 4 + j;
            if (transp) out[(size_t)col * NROWS + row] = val;   // kpT[d][m]
            else        out[(size_t)row * DDIM  + col] = val;
        }
    }
}

// ---------------- Score kernel: S[n,m] = -2 * sum_d Ww[d] * rcp(1+exp2(qp'+kpT')) --
// Block: 256 threads = 4 waves. Wave w -> row n = by*4+w. Lane -> m = bx*64+lane.
// kpT chunk (128 d x 64 m) staged in LDS; qp row + Ww read via wave-uniform
// (scalar) loads.
__global__ __launch_bounds__(256) void score_kernel(const float* __restrict__ qp,
                                                    const float* __restrict__ kpT,
                                                    const float* __restrict__ Ww,
                                                    float* __restrict__ S)
{
    __shared__ float ks[128 * 64];   // 32 KB
    const int t    = threadIdx.x;
    const int lane = t & 63;
    const int w    = t >> 6;
    const int m0   = blockIdx.x * 64;
    const int n    = blockIdx.y * 4 + w;
    const int nu   = __builtin_amdgcn_readfirstlane(n);
    const float* __restrict__ qrow = qp + (size_t)nu * DDIM;

    float acc = 0.0f;

    for (int d0 = 0; d0 < DDIM; d0 += 128) {
        __syncthreads();
#pragma unroll
        for (int i = 0; i < 32; ++i) {
            int idx = t + i * 256;
            int r = idx >> 6, c = idx & 63;
            ks[r * 64 + c] = kpT[(size_t)(d0 + r) * MDIM + m0 + c];
        }
        __syncthreads();
#pragma unroll 8
        for (int dd = 0; dd < 128; ++dd) {
            int d = d0 + dd;
            float xv = qrow[d] + ks[dd * 64 + lane];        // lds: 2-way = free
            float e  = __builtin_amdgcn_exp2f(xv);          // e^{2(qp+kp)}
            float r  = __builtin_amdgcn_rcpf(1.0f + e);
            acc = fmaf(Ww[d], r, acc);
        }
    }
    S[(size_t)n * MDIM + m0 + lane] = -2.0f * acc;
}

// ---------------- Softmax (in place over S), mask -> weight 0 ----------------
__global__ __launch_bounds__(256) void softmax_kernel(float* __restrict__ S,
                                                      const int* __restrict__ mask)
{
    const int n = blockIdx.x, t = threadIdx.x;
    const int lane = t & 63, w = t >> 6;
    __shared__ float red[8];

    float4 s  = ((const float4*)(S + (size_t)n * MDIM))[t];
    int4   mk = ((const int4*)(mask + (size_t)n * MDIM))[t];

    const float NEG = -3.0e38f;
    float mx = fmaxf(fmaxf(mk.x ? s.x : NEG, mk.y ? s.y : NEG),
                     fmaxf(mk.z ? s.z : NEG, mk.w ? s.w : NEG));
#pragma unroll
    for (int off = 32; off; off >>= 1) mx = fmaxf(mx, __shfl_xor(mx, off));
    if (lane == 0) red[w] = mx;
    __syncthreads();
    float rowmax = fmaxf(fmaxf(red[0], red[1]), fmaxf(red[2], red[3]));

    const float L2E = 1.4426950408889634f;
    float p0 = mk.x ? __builtin_amdgcn_exp2f((s.x - rowmax) * L2E) : 0.0f;
    float p1 = mk.y ? __builtin_amdgcn_exp2f((s.y - rowmax) * L2E) : 0.0f;
    float p2 = mk.z ? __builtin_amdgcn_exp2f((s.z - rowmax) * L2E) : 0.0f;
    float p3 = mk.w ? __builtin_amdgcn_exp2f((s.w - rowmax) * L2E) : 0.0f;
    float sum = (p0 + p1) + (p2 + p3);
#pragma unroll
    for (int off = 32; off; off >>= 1) sum += __shfl_xor(sum, off);
    if (lane == 0) red[4 + w] = sum;
    __syncthreads();
    float tot = (red[4] + red[5]) + (red[6] + red[7]);
    float inv = __builtin_amdgcn_rcpf(tot);

    float4 o = {p0 * inv, p1 * inv, p2 * inv, p3 * inv};
    ((float4*)(S + (size_t)n * MDIM))[t] = o;
}

// ---------------- Context GEMM: out[n,d] = sum_m attn[n,m] * vp[m,d] ---------
// 32(n) x 64(d) tile per block, k-chunks of 64 over m.
__global__ __launch_bounds__(256) void ctx_gemm(const float* __restrict__ attn,
                                                const float* __restrict__ vp,
                                                float* __restrict__ out)
{
    __shared__ float as[32 * 65];
    __shared__ float vs[64 * 68];
    const int t  = threadIdx.x;
    const int tx = t & 15;      // 16 col groups of 4
    const int ty = t >> 4;      // 16 row groups of 2
    const int i0 = blockIdx.y * 32;   // n rows
    const int d0 = blockIdx.x * 64;   // d cols

    float acc[2][4] = {};

    for (int m0 = 0; m0 < MDIM; m0 += 64) {
        __syncthreads();
#pragma unroll
        for (int i = 0; i < 8; ++i) {
            int idx = t + i * 256;
            int r = idx >> 6, c = idx & 63;
            as[r * 65 + c] = attn[(size_t)(i0 + r) * MDIM + m0 + c];
        }
#pragma unroll
        for (int i = 0; i < 16; ++i) {
            int idx = t + i * 256;
            int r = idx >> 6, c = idx & 63;
            vs[r * 68 + c] = vp[(size_t)(m0 + r) * DDIM + d0 + c];
        }
        __syncthreads();
#pragma unroll
        for (int k = 0; k < 64; ++k) {
            float a0 = as[(ty * 2 + 0) * 65 + k];
            float a1 = as[(ty * 2 + 1) * 65 + k];
            float4 b = *(const float4*)&vs[k * 68 + tx * 4];
            acc[0][0] = fmaf(a0, b.x, acc[0][0]);
            acc[0][1] = fmaf(a0, b.y, acc[0][1]);
            acc[0][2] = fmaf(a0, b.z, acc[0][2]);
            acc[0][3] = fmaf(a0, b.w, acc[0][3]);
            acc[1][0] = fmaf(a1, b.x, acc[1][0]);
            acc[1][1] = fmaf(a1, b.y, acc[1][1]);
            acc[1][2] = fmaf(a1, b.z, acc[1][2]);
            acc[1][3] = fmaf(a1, b.w, acc[1][3]);
        }
    }
    float4 o0 = {acc[0][0], acc[0][1], acc[0][2], acc[0][3]};
    float4 o1 = {acc[1][0], acc[1][1], acc[1][2], acc[1][3]};
    *(float4*)&out[(size_t)(i0 + ty * 2 + 0) * DDIM + d0 + tx * 4] = o0;
    *(float4*)&out[(size_t)(i0 + ty * 2 + 1) * DDIM + d0 + tx * 4] = o1;
}

extern "C" void kernel_launch(void* const* d_in, const int* in_sizes, int n_in,
                              void* d_out, int out_size, void* d_ws, size_t ws_size,
                              hipStream_t stream)
{
    const float* q    = (const float*)d_in[0];
    const float* k    = (const float*)d_in[1];
    const float* v    = (const float*)d_in[2];
    const int*   mask = (const int*)d_in[3];
    const float* Wq   = (const float*)d_in[4];
    const float* bq   = (const float*)d_in[5];
    const float* Wk   = (const float*)d_in[6];
    const float* bk   = (const float*)d_in[7];
    const float* Wv   = (const float*)d_in[8];
    const float* bv   = (const float*)d_in[9];
    const float* Ww   = (const float*)d_in[10];
    // d_in[11] (bw) cancels under softmax -> unused.

    float* ws  = (float*)d_ws;
    float* qp  = ws;                        // 1024*512
    float* kpT = ws + 512 * 1024;           // 512*1024 (transposed)
    float* vp  = ws + 2 * 512 * 1024;       // 1024*512
    float* S   = ws + 3 * 512 * 1024;       // 1024*1024 (scores, then attn)
    float* out = (float*)d_out;

    const float CS = 2.8853900817779268f;   // 2*log2(e)

    dim3 b256(256);
    dim3 gA(8, 16);
    proj_gemm<<<gA, b256, 0, stream>>>(q, Wq, bq, qp,  CS,   0);
    proj_gemm<<<gA, b256, 0, stream>>>(k, Wk, bk, kpT, CS,   1);
    proj_gemm<<<gA, b256, 0, stream>>>(v, Wv, bv, vp,  1.0f, 0);
    score_kernel<<<dim3(16, 256), b256, 0, stream>>>(qp, kpT, Ww, S);
    softmax_kernel<<<dim3(1024), b256, 0, stream>>>(S, mask);
    ctx_gemm<<<dim3(8, 32), b256, 0, stream>>>(S, vp, out);
}

// Round 2
// 253.758 us; speedup vs baseline: 1.4973x; 1.4973x over previous
//
#include <hip/hip_runtime.h>
#include <hip/hip_bf16.h>
#include <float.h>

// Problem: N=1024, M=1024, D=512. All fp32.
// ws layout (floats): qp[1024*512] | kpT[512*1024] | vp[1024*512] | S[1024*1024]
// qp,kpT pre-scaled by 2*log2(e) so tanh(q+k) = 1 - 2*rcp(1+exp2(qp'+kpT')).
// Softmax is shift-invariant -> drop (bw + sum(Ww)) entirely.

#define NROWS 1024
#define DDIM  512
#define MDIM  1024

__device__ __forceinline__ void load_lds16(const float* g, float* l) {
    __builtin_amdgcn_global_load_lds(
        (const __attribute__((address_space(1))) void*)g,
        (__attribute__((address_space(3))) void*)l, 16, 0, 0);
}

// ---------------- Fused projection GEMMs: out = (x @ W.T + b) * scale --------
// blockIdx.z selects {q,k,v}. 64x64 tile, 4x4 per thread, both LDS tiles
// stored k-major so A and B fragments are ds_read_b128.
__global__ __launch_bounds__(256) void proj_gemm(
    const float* __restrict__ q, const float* __restrict__ kk_,
    const float* __restrict__ v,
    const float* __restrict__ Wq, const float* __restrict__ bq,
    const float* __restrict__ Wk, const float* __restrict__ bk,
    const float* __restrict__ Wv, const float* __restrict__ bv,
    float* __restrict__ qp, float* __restrict__ kpT, float* __restrict__ vp,
    float CS)
{
    __shared__ __align__(16) float xsT[64 * 68];   // [k][row]
    __shared__ __align__(16) float wsT[64 * 68];   // [k][col]

    const float* x; const float* W; const float* bias; float scale; int transp;
    float* out;
    if (blockIdx.z == 0)      { x = q;   W = Wq; bias = bq; out = qp;  scale = CS;   transp = 0; }
    else if (blockIdx.z == 1) { x = kk_; W = Wk; bias = bk; out = kpT; scale = CS;   transp = 1; }
    else                      { x = v;   W = Wv; bias = bv; out = vp;  scale = 1.0f; transp = 0; }

    const int t  = threadIdx.x;
    const int tx = t & 15;            // 16 col groups of 4
    const int ty = t >> 4;            // 16 row groups of 4
    const int i0 = blockIdx.y * 64;   // rows
    const int j0 = blockIdx.x * 64;   // out cols

    float acc[4][4] = {};

    for (int k0 = 0; k0 < DDIM; k0 += 64) {
        __syncthreads();
#pragma unroll
        for (int i = 0; i < 16; ++i) {
            int idx = t + i * 256;
            int r = idx >> 6, c = idx & 63;     // consecutive lanes -> consecutive c
            xsT[c * 68 + r] = x[(size_t)(i0 + r) * DDIM + k0 + c];
            wsT[c * 68 + r] = W[(size_t)(j0 + r) * DDIM + k0 + c];
        }
        __syncthreads();
#pragma unroll
        for (int k = 0; k < 64; ++k) {
            float4 a = *(const float4*)&xsT[k * 68 + ty * 4];
            float4 b = *(const float4*)&wsT[k * 68 + tx * 4];
            float av[4] = {a.x, a.y, a.z, a.w};
            float bv4[4] = {b.x, b.y, b.z, b.w};
#pragma unroll
            for (int i = 0; i < 4; ++i)
#pragma unroll
                for (int j = 0; j < 4; ++j)
                    acc[i][j] = fmaf(av[i], bv4[j], acc[i][j]);
        }
    }

#pragma unroll
    for (int j = 0; j < 4; ++j) {
        float bv = bias[j0 + tx * 4 + j];
#pragma unroll
        for (int i = 0; i < 4; ++i) {
            float val = (acc[i][j] + bv) * scale;
            int row = i0 + ty * 4 + i;
            int col = j0 + tx * 4 + j;
            if (transp) out[(size_t)col * NROWS + row] = val;   // kpT[d][m]
            else        out[(size_t)row * DDIM  + col] = val;
        }
    }
}

// ---------------- Score kernel V2 --------------------------------------------
// S[n,m] = -2 * sum_d Ww[d] * rcp(1+exp2(qp'[n,d]+kpT'[d,m]))
// Block: 256 thr = 4 waves. Wave w -> row n = by*4+w. Lane -> m = bx*256+lane*4 (+0..3).
// ks chunk [32 d][256 m] staged with global_load_lds width=16 (dest = base+lane*16,
// matches packed row layout). q rows + Ww staged in LDS, amortized over 4 m/lane.
#define DCH 32
__global__ __launch_bounds__(256) void score_kernel(const float* __restrict__ qp,
                                                    const float* __restrict__ kpT,
                                                    const float* __restrict__ Ww,
                                                    float* __restrict__ S)
{
    __shared__ __align__(16) float ks[DCH * 256];   // 32 KB, rows of 1 KB
    __shared__ float qs[4 * DCH];
    __shared__ float wws[DCH];

    const int t    = threadIdx.x;
    const int lane = t & 63;
    const int w    = t >> 6;
    const int m0   = blockIdx.x * 256;
    const int n    = blockIdx.y * 4 + w;

    float acc0 = 0.f, acc1 = 0.f, acc2 = 0.f, acc3 = 0.f;

    for (int d0 = 0; d0 < DDIM; d0 += DCH) {
        __syncthreads();
        // wave w stages ks rows w*8 .. w*8+7 (1 KB per wave-instruction)
#pragma unroll
        for (int i = 0; i < 8; ++i) {
            int r = w * 8 + i;                                   // wave-uniform
            load_lds16(kpT + (size_t)(d0 + r) * MDIM + m0 + lane * 4,
                       &ks[r * 256]);
        }
        if (t < 128) {
            int wq = t >> 5, dd = t & 31;
            qs[wq * DCH + dd] = qp[(size_t)(blockIdx.y * 4 + wq) * DDIM + d0 + dd];
        } else if (t < 160) {
            wws[t - 128] = Ww[d0 + t - 128];
        }
        __syncthreads();   // drains vmcnt -> global_load_lds data visible

#pragma unroll
        for (int dd = 0; dd < DCH; ++dd) {
            float qv = qs[w * DCH + dd];
            float wv = wws[dd];
            float4 kv = *(const float4*)&ks[dd * 256 + lane * 4];
            float e0 = __builtin_amdgcn_exp2f(qv + kv.x);
            float e1 = __builtin_amdgcn_exp2f(qv + kv.y);
            float e2 = __builtin_amdgcn_exp2f(qv + kv.z);
            float e3 = __builtin_amdgcn_exp2f(qv + kv.w);
            acc0 = fmaf(wv, __builtin_amdgcn_rcpf(1.0f + e0), acc0);
            acc1 = fmaf(wv, __builtin_amdgcn_rcpf(1.0f + e1), acc1);
            acc2 = fmaf(wv, __builtin_amdgcn_rcpf(1.0f + e2), acc2);
            acc3 = fmaf(wv, __builtin_amdgcn_rcpf(1.0f + e3), acc3);
        }
    }
    float4 o = {-2.0f * acc0, -2.0f * acc1, -2.0f * acc2, -2.0f * acc3};
    *(float4*)&S[(size_t)n * MDIM + m0 + lane * 4] = o;
}

// ---------------- Softmax (in place over S), mask -> weight 0 ----------------
__global__ __launch_bounds__(256) void softmax_kernel(float* __restrict__ S,
                                                      const int* __restrict__ mask)
{
    const int n = blockIdx.x, t = threadIdx.x;
    const int lane = t & 63, w = t >> 6;
    __shared__ float red[8];

    float4 s  = ((const float4*)(S + (size_t)n * MDIM))[t];
    int4   mk = ((const int4*)(mask + (size_t)n * MDIM))[t];

    const float NEG = -3.0e38f;
    float mx = fmaxf(fmaxf(mk.x ? s.x : NEG, mk.y ? s.y : NEG),
                     fmaxf(mk.z ? s.z : NEG, mk.w ? s.w : NEG));
#pragma unroll
    for (int off = 32; off; off >>= 1) mx = fmaxf(mx, __shfl_xor(mx, off));
    if (lane == 0) red[w] = mx;
    __syncthreads();
    float rowmax = fmaxf(fmaxf(red[0], red[1]), fmaxf(red[2], red[3]));

    const float L2E = 1.4426950408889634f;
    float p0 = mk.x ? __builtin_amdgcn_exp2f((s.x - rowmax) * L2E) : 0.0f;
    float p1 = mk.y ? __builtin_amdgcn_exp2f((s.y - rowmax) * L2E) : 0.0f;
    float p2 = mk.z ? __builtin_amdgcn_exp2f((s.z - rowmax) * L2E) : 0.0f;
    float p3 = mk.w ? __builtin_amdgcn_exp2f((s.w - rowmax) * L2E) : 0.0f;
    float sum = (p0 + p1) + (p2 + p3);
#pragma unroll
    for (int off = 32; off; off >>= 1) sum += __shfl_xor(sum, off);
    if (lane == 0) red[4 + w] = sum;
    __syncthreads();
    float tot = (red[4] + red[5]) + (red[6] + red[7]);
    float inv = __builtin_amdgcn_rcpf(tot);

    float4 o = {p0 * inv, p1 * inv, p2 * inv, p3 * inv};
    ((float4*)(S + (size_t)n * MDIM))[t] = o;
}

// ---------------- Context GEMM: out[n,d] = sum_m attn[n,m] * vp[m,d] ---------
// 32(n) x 64(d) tile per block; A stored k-major in LDS for float2 reads.
__global__ __launch_bounds__(256) void ctx_gemm(const float* __restrict__ attn,
                                                const float* __restrict__ vp,
                                                float* __restrict__ out)
{
    __shared__ __align__(16) float asT[64 * 34];   // [m-k][n-row], stride 34
    __shared__ __align__(16) float vs[64 * 68];    // [m-k][d-col], stride 68
    const int t  = threadIdx.x;
    const int tx = t & 15;      // 16 col groups of 4
    const int ty = t >> 4;      // 16 row groups of 2
    const int i0 = blockIdx.y * 32;   // n rows
    const int d0 = blockIdx.x * 64;   // d cols

    float acc[2][4] = {};

    for (int m0 = 0; m0 < MDIM; m0 += 64) {
        __syncthreads();
#pragma unroll
        for (int i = 0; i < 8; ++i) {
            int idx = t + i * 256;
            int r = idx >> 6, c = idx & 63;     // r: n-row 0..31, c: m 0..63
            asT[c * 34 + r] = attn[(size_t)(i0 + r) * MDIM + m0 + c];
        }
#pragma unroll
        for (int i = 0; i < 16; ++i) {
            int idx = t + i * 256;
            int r = idx >> 6, c = idx & 63;
            vs[r * 68 + c] = vp[(size_t)(m0 + r) * DDIM + d0 + c];
        }
        __syncthreads();
#pragma unroll
        for (int k = 0; k < 64; ++k) {
            float2 a = *(const float2*)&asT[k * 34 + ty * 2];
            float4 b = *(const float4*)&vs[k * 68 + tx * 4];
            acc[0][0] = fmaf(a.x, b.x, acc[0][0]);
            acc[0][1] = fmaf(a.x, b.y, acc[0][1]);
            acc[0][2] = fmaf(a.x, b.z, acc[0][2]);
            acc[0][3] = fmaf(a.x, b.w, acc[0][3]);
            acc[1][0] = fmaf(a.y, b.x, acc[1][0]);
            acc[1][1] = fmaf(a.y, b.y, acc[1][1]);
            acc[1][2] = fmaf(a.y, b.z, acc[1][2]);
            acc[1][3] = fmaf(a.y, b.w, acc[1][3]);
        }
    }
    float4 o0 = {acc[0][0], acc[0][1], acc[0][2], acc[0][3]};
    float4 o1 = {acc[1][0], acc[1][1], acc[1][2], acc[1][3]};
    *(float4*)&out[(size_t)(i0 + ty * 2 + 0) * DDIM + d0 + tx * 4] = o0;
    *(float4*)&out[(size_t)(i0 + ty * 2 + 1) * DDIM + d0 + tx * 4] = o1;
}

extern "C" void kernel_launch(void* const* d_in, const int* in_sizes, int n_in,
                              void* d_out, int out_size, void* d_ws, size_t ws_size,
                              hipStream_t stream)
{
    const float* q    = (const float*)d_in[0];
    const float* k    = (const float*)d_in[1];
    const float* v    = (const float*)d_in[2];
    const int*   mask = (const int*)d_in[3];
    const float* Wq   = (const float*)d_in[4];
    const float* bq   = (const float*)d_in[5];
    const float* Wk   = (const float*)d_in[6];
    const float* bk   = (const float*)d_in[7];
    const float* Wv   = (const float*)d_in[8];
    const float* bv   = (const float*)d_in[9];
    const float* Ww   = (const float*)d_in[10];
    // d_in[11] (bw) cancels under softmax -> unused.

    float* ws  = (float*)d_ws;
    float* qp  = ws;                        // 1024*512
    float* kpT = ws + 512 * 1024;           // 512*1024 (transposed)
    float* vp  = ws + 2 * 512 * 1024;       // 1024*512
    float* S   = ws + 3 * 512 * 1024;       // 1024*1024 (scores, then attn)
    float* out = (float*)d_out;

    const float CS = 2.8853900817779268f;   // 2*log2(e)

    dim3 b256(256);
    proj_gemm<<<dim3(8, 16, 3), b256, 0, stream>>>(q, k, v, Wq, bq, Wk, bk,
                                                   Wv, bv, qp, kpT, vp, CS);
    score_kernel<<<dim3(4, 256), b256, 0, stream>>>(qp, kpT, Ww, S);
    softmax_kernel<<<dim3(1024), b256, 0, stream>>>(S, mask);
    ctx_gemm<<<dim3(8, 32), b256, 0, stream>>>(S, vp, out);
}

// Round 3
// 217.833 us; speedup vs baseline: 1.7443x; 1.1649x over previous
//
#include <hip/hip_runtime.h>
#include <hip/hip_bf16.h>
#include <float.h>

// N=1024, M=1024, D=512, fp32.
// tanh(q+k) = 1 - 2/(1+exp2(CS*(q+k))), CS = 2*log2(e).
// exp2 factorizes: exp2(CS*q)*exp2(CS*k) -> precompute eq, ekT in proj epilogue.
// Score: S[n,m] = -2 * sum_d Ww[d] * rcp(1 + eq[n,d]*ekT[d,m])  (+row-const dropped:
// softmax shift-invariant).
// ws: eq[1024*512] | ekT[512*1024] | vp[1024*512] | S[1024*1024]

#define NROWS 1024
#define DDIM  512
#define MDIM  1024

__device__ __forceinline__ void load_lds16(const float* g, float* l) {
    __builtin_amdgcn_global_load_lds(
        (const __attribute__((address_space(1))) void*)g,
        (__attribute__((address_space(3))) void*)l, 16, 0, 0);
}

// ---------------- Fused projection GEMMs ------------------------------------
// z=0: eq = exp2((q@Wq.T+bq)*CS)         [row-major 1024x512]
// z=1: ekT = exp2((k@Wk.T+bk)*CS)^T      [512x1024]
// z=2: vp = v@Wv.T+bv                    [row-major 1024x512]
// 64x64 tile, 4x4/thread. LDS k-major stride 68 (16B-aligned reads).
// Staging: lanes sweep row dim -> ds_write bank = const+lane (conflict-free).
__global__ __launch_bounds__(256) void proj_gemm(
    const float* __restrict__ q, const float* __restrict__ kk_,
    const float* __restrict__ v,
    const float* __restrict__ Wq, const float* __restrict__ bq,
    const float* __restrict__ Wk, const float* __restrict__ bk,
    const float* __restrict__ Wv, const float* __restrict__ bv,
    float* __restrict__ eq, float* __restrict__ ekT, float* __restrict__ vp,
    float CS)
{
    __shared__ __align__(16) float xsT[64 * 68];   // [k][row]
    __shared__ __align__(16) float wsT[64 * 68];   // [k][outcol]

    const float* x; const float* W; const float* bias;
    if (blockIdx.z == 0)      { x = q;   W = Wq; bias = bq; }
    else if (blockIdx.z == 1) { x = kk_; W = Wk; bias = bk; }
    else                      { x = v;   W = Wv; bias = bv; }

    const int t  = threadIdx.x;
    const int tx = t & 15;
    const int ty = t >> 4;
    const int i0 = blockIdx.y * 64;
    const int j0 = blockIdx.x * 64;

    float acc[4][4] = {};

    for (int k0 = 0; k0 < DDIM; k0 += 64) {
        __syncthreads();
        // 1024 float4s per tile; r = lane (conflict-free transposed stores)
#pragma unroll
        for (int i = 0; i < 4; ++i) {
            int idx = t + i * 256;
            int r = idx & 63, kq = idx >> 6;            // r==lane, kq wave-uniform
            float4 xf = *(const float4*)&x[(size_t)(i0 + r) * DDIM + k0 + kq * 4];
            float4 wf = *(const float4*)&W[(size_t)(j0 + r) * DDIM + k0 + kq * 4];
            xsT[(4 * kq + 0) * 68 + r] = xf.x;
            xsT[(4 * kq + 1) * 68 + r] = xf.y;
            xsT[(4 * kq + 2) * 68 + r] = xf.z;
            xsT[(4 * kq + 3) * 68 + r] = xf.w;
            wsT[(4 * kq + 0) * 68 + r] = wf.x;
            wsT[(4 * kq + 1) * 68 + r] = wf.y;
            wsT[(4 * kq + 2) * 68 + r] = wf.z;
            wsT[(4 * kq + 3) * 68 + r] = wf.w;
        }
        __syncthreads();
#pragma unroll
        for (int k = 0; k < 64; ++k) {
            float4 a = *(const float4*)&xsT[k * 68 + ty * 4];   // broadcast
            float4 b = *(const float4*)&wsT[k * 68 + tx * 4];   // canonical
            float av[4] = {a.x, a.y, a.z, a.w};
            float bv4[4] = {b.x, b.y, b.z, b.w};
#pragma unroll
            for (int i = 0; i < 4; ++i)
#pragma unroll
                for (int j = 0; j < 4; ++j)
                    acc[i][j] = fmaf(av[i], bv4[j], acc[i][j]);
        }
    }

#pragma unroll
    for (int j = 0; j < 4; ++j) {
        float bv = bias[j0 + tx * 4 + j];
#pragma unroll
        for (int i = 0; i < 4; ++i) {
            float val = acc[i][j] + bv;
            int row = i0 + ty * 4 + i;
            int col = j0 + tx * 4 + j;
            if (blockIdx.z == 0)
                eq[(size_t)row * DDIM + col] = __builtin_amdgcn_exp2f(val * CS);
            else if (blockIdx.z == 1)
                ekT[(size_t)col * MDIM + row] = __builtin_amdgcn_exp2f(val * CS);
            else
                vp[(size_t)row * DDIM + col] = val;
        }
    }
}

// ---------------- Score kernel ----------------------------------------------
// S[n,m] = -2 * sum_d Ww[d] * rcp(1 + eq[n,d]*ekT[d,m])
// 4 waves; wave w -> row n = by*4+w; lane -> 4 m's. ekT chunk [32 d][256 m]
// via global_load_lds width=16.
#define DCH 32
__global__ __launch_bounds__(256) void score_kernel(const float* __restrict__ eq,
                                                    const float* __restrict__ ekT,
                                                    const float* __restrict__ Ww,
                                                    float* __restrict__ S)
{
    __shared__ __align__(16) float ks[DCH * 256];   // 32 KB
    __shared__ float qs[4 * DCH];
    __shared__ float wws[DCH];

    const int t    = threadIdx.x;
    const int lane = t & 63;
    const int w    = t >> 6;
    const int m0   = blockIdx.x * 256;
    const int n    = blockIdx.y * 4 + w;

    float acc0 = 0.f, acc1 = 0.f, acc2 = 0.f, acc3 = 0.f;

    for (int d0 = 0; d0 < DDIM; d0 += DCH) {
        __syncthreads();
#pragma unroll
        for (int i = 0; i < 8; ++i) {
            int r = w * 8 + i;                                   // wave-uniform
            load_lds16(ekT + (size_t)(d0 + r) * MDIM + m0 + lane * 4,
                       &ks[r * 256]);
        }
        if (t < 128) {
            int wq = t >> 5, dd = t & 31;
            qs[wq * DCH + dd] = eq[(size_t)(blockIdx.y * 4 + wq) * DDIM + d0 + dd];
        } else if (t < 160) {
            wws[t - 128] = Ww[d0 + t - 128];
        }
        __syncthreads();

#pragma unroll
        for (int dd = 0; dd < DCH; ++dd) {
            float eqv = qs[w * DCH + dd];
            float wv  = wws[dd];
            float4 kv = *(const float4*)&ks[dd * 256 + lane * 4];
            acc0 = fmaf(wv, __builtin_amdgcn_rcpf(fmaf(eqv, kv.x, 1.0f)), acc0);
            acc1 = fmaf(wv, __builtin_amdgcn_rcpf(fmaf(eqv, kv.y, 1.0f)), acc1);
            acc2 = fmaf(wv, __builtin_amdgcn_rcpf(fmaf(eqv, kv.z, 1.0f)), acc2);
            acc3 = fmaf(wv, __builtin_amdgcn_rcpf(fmaf(eqv, kv.w, 1.0f)), acc3);
        }
    }
    float4 o = {-2.0f * acc0, -2.0f * acc1, -2.0f * acc2, -2.0f * acc3};
    *(float4*)&S[(size_t)n * MDIM + m0 + lane * 4] = o;
}

// ---------------- Softmax (in place over S), mask -> weight 0 ----------------
__global__ __launch_bounds__(256) void softmax_kernel(float* __restrict__ S,
                                                      const int* __restrict__ mask)
{
    const int n = blockIdx.x, t = threadIdx.x;
    const int lane = t & 63, w = t >> 6;
    __shared__ float red[8];

    float4 s  = ((const float4*)(S + (size_t)n * MDIM))[t];
    int4   mk = ((const int4*)(mask + (size_t)n * MDIM))[t];

    const float NEG = -3.0e38f;
    float mx = fmaxf(fmaxf(mk.x ? s.x : NEG, mk.y ? s.y : NEG),
                     fmaxf(mk.z ? s.z : NEG, mk.w ? s.w : NEG));
#pragma unroll
    for (int off = 32; off; off >>= 1) mx = fmaxf(mx, __shfl_xor(mx, off));
    if (lane == 0) red[w] = mx;
    __syncthreads();
    float rowmax = fmaxf(fmaxf(red[0], red[1]), fmaxf(red[2], red[3]));

    const float L2E = 1.4426950408889634f;
    float p0 = mk.x ? __builtin_amdgcn_exp2f((s.x - rowmax) * L2E) : 0.0f;
    float p1 = mk.y ? __builtin_amdgcn_exp2f((s.y - rowmax) * L2E) : 0.0f;
    float p2 = mk.z ? __builtin_amdgcn_exp2f((s.z - rowmax) * L2E) : 0.0f;
    float p3 = mk.w ? __builtin_amdgcn_exp2f((s.w - rowmax) * L2E) : 0.0f;
    float sum = (p0 + p1) + (p2 + p3);
#pragma unroll
    for (int off = 32; off; off >>= 1) sum += __shfl_xor(sum, off);
    if (lane == 0) red[4 + w] = sum;
    __syncthreads();
    float tot = (red[4] + red[5]) + (red[6] + red[7]);
    float inv = __builtin_amdgcn_rcpf(tot);

    float4 o = {p0 * inv, p1 * inv, p2 * inv, p3 * inv};
    ((float4*)(S + (size_t)n * MDIM))[t] = o;
}

// ---------------- Context GEMM: out[n,d] = sum_m attn[n,m]*vp[m,d] ----------
// 32(n) x 64(d) tile, 256 blocks. A k-major (transposed, conflict-free),
// B natural row-major stride 68 (b128 stage + b128 read).
__global__ __launch_bounds__(256) void ctx_gemm(const float* __restrict__ attn,
                                                const float* __restrict__ vp,
                                                float* __restrict__ out)
{
    __shared__ __align__(16) float asT[64 * 34];   // [m-k][n-row]
    __shared__ __align__(16) float vs[64 * 68];    // [m-k][d-col]
    const int t  = threadIdx.x;
    const int tx = t & 15;
    const int ty = t >> 4;                 // 0..15
    const int i0 = blockIdx.y * 32;
    const int d0 = blockIdx.x * 64;

    float acc[2][4] = {};

    for (int m0 = 0; m0 < MDIM; m0 += 64) {
        __syncthreads();
        // attn tile 32 rows x 64 m -> asT[k][row], lanes sweep rows
#pragma unroll
        for (int i = 0; i < 2; ++i) {
            int idx = t + i * 256;
            int r = idx & 31, kq = idx >> 5;           // r==lane&31, kq uniform-ish
            float4 af = *(const float4*)&attn[(size_t)(i0 + r) * MDIM + m0 + kq * 4];
            asT[(4 * kq + 0) * 34 + r] = af.x;
            asT[(4 * kq + 1) * 34 + r] = af.y;
            asT[(4 * kq + 2) * 34 + r] = af.z;
            asT[(4 * kq + 3) * 34 + r] = af.w;
        }
        // vp tile 64 m x 64 d -> vs row-major (direct b128 copy)
#pragma unroll
        for (int i = 0; i < 4; ++i) {
            int idx = t + i * 256;
            int r = idx >> 4, c4 = idx & 15;
            float4 vf = *(const float4*)&vp[(size_t)(m0 + r) * DDIM + d0 + c4 * 4];
            *(float4*)&vs[r * 68 + c4 * 4] = vf;
        }
        __syncthreads();
#pragma unroll
        for (int k = 0; k < 64; ++k) {
            float2 a = *(const float2*)&asT[k * 34 + ty * 2];   // broadcast
            float4 b = *(const float4*)&vs[k * 68 + tx * 4];    // canonical
            acc[0][0] = fmaf(a.x, b.x, acc[0][0]);
            acc[0][1] = fmaf(a.x, b.y, acc[0][1]);
            acc[0][2] = fmaf(a.x, b.z, acc[0][2]);
            acc[0][3] = fmaf(a.x, b.w, acc[0][3]);
            acc[1][0] = fmaf(a.y, b.x, acc[1][0]);
            acc[1][1] = fmaf(a.y, b.y, acc[1][1]);
            acc[1][2] = fmaf(a.y, b.z, acc[1][2]);
            acc[1][3] = fmaf(a.y, b.w, acc[1][3]);
        }
    }
    float4 o0 = {acc[0][0], acc[0][1], acc[0][2], acc[0][3]};
    float4 o1 = {acc[1][0], acc[1][1], acc[1][2], acc[1][3]};
    *(float4*)&out[(size_t)(i0 + ty * 2 + 0) * DDIM + d0 + tx * 4] = o0;
    *(float4*)&out[(size_t)(i0 + ty * 2 + 1) * DDIM + d0 + tx * 4] = o1;
}

extern "C" void kernel_launch(void* const* d_in, const int* in_sizes, int n_in,
                              void* d_out, int out_size, void* d_ws, size_t ws_size,
                              hipStream_t stream)
{
    const float* q    = (const float*)d_in[0];
    const float* k    = (const float*)d_in[1];
    const float* v    = (const float*)d_in[2];
    const int*   mask = (const int*)d_in[3];
    const float* Wq   = (const float*)d_in[4];
    const float* bq   = (const float*)d_in[5];
    const float* Wk   = (const float*)d_in[6];
    const float* bk   = (const float*)d_in[7];
    const float* Wv   = (const float*)d_in[8];
    const float* bv   = (const float*)d_in[9];
    const float* Ww   = (const float*)d_in[10];
    // d_in[11] (bw) cancels under softmax.

    float* ws  = (float*)d_ws;
    float* eq  = ws;
    float* ekT = ws + 512 * 1024;
    float* vp  = ws + 2 * 512 * 1024;
    float* S   = ws + 3 * 512 * 1024;
    float* out = (float*)d_out;

    const float CS = 2.8853900817779268f;   // 2*log2(e)

    dim3 b256(256);
    proj_gemm<<<dim3(8, 16, 3), b256, 0, stream>>>(q, k, v, Wq, bq, Wk, bk,
                                                   Wv, bv, eq, ekT, vp, CS);
    score_kernel<<<dim3(4, 256), b256, 0, stream>>>(eq, ekT, Ww, S);
    softmax_kernel<<<dim3(1024), b256, 0, stream>>>(S, mask);
    ctx_gemm<<<dim3(8, 32), b256, 0, stream>>>(S, vp, out);
}

// Round 4
// 204.542 us; speedup vs baseline: 1.8576x; 1.0650x over previous
//
#include <hip/hip_runtime.h>
#include <hip/hip_bf16.h>
#include <float.h>

// N=1024, M=1024, D=512, fp32.
// tanh(q+k) = 1 - 2/(1+exp2(CS*(q+k))), CS = 2*log2(e); exp2 factorized:
// eq=exp2(CS*qp), ekT=exp2(CS*kp)^T  ->  score s = -2*sum_d Ww[d]*rcp(1+eq*ek)
// (row-const dropped: softmax shift-invariant). |s|<=2*sum|Ww|~36 -> exp(s)
// never overflows fp32 => NO max pass. P = mask ? exp(s) : 0 written directly
// by score kernel; ctx computes unnormalized C = P@vp (m-split partials);
// combine divides by rowsum(P).
// ws (floats): eq[512K] ekT[512K] vp[512K] P[1M] C0[512K] C1[512K] = 14 MB.

#define NROWS 1024
#define DDIM  512
#define MDIM  1024

typedef float v2f __attribute__((ext_vector_type(2)));

__device__ __forceinline__ void load_lds16(const float* g, float* l) {
    __builtin_amdgcn_global_load_lds(
        (const __attribute__((address_space(1))) void*)g,
        (__attribute__((address_space(3))) void*)l, 16, 0, 0);
}

// ---------------- Fused projection GEMMs ------------------------------------
// z=0: eq = exp2((q@Wq.T+bq)*CS)   z=1: ekT = exp2((k@Wk.T+bk)*CS)^T
// z=2: vp = v@Wv.T+bv
// 64x64 tile, 4x4/thread, LDS k-major stride 68, conflict-free transposed
// stores (lanes sweep row dim).
__global__ __launch_bounds__(256) void proj_gemm(
    const float* __restrict__ q, const float* __restrict__ kk_,
    const float* __restrict__ v,
    const float* __restrict__ Wq, const float* __restrict__ bq,
    const float* __restrict__ Wk, const float* __restrict__ bk,
    const float* __restrict__ Wv, const float* __restrict__ bv,
    float* __restrict__ eq, float* __restrict__ ekT, float* __restrict__ vp,
    float CS)
{
    __shared__ __align__(16) float xsT[64 * 68];
    __shared__ __align__(16) float wsT[64 * 68];

    const float* x; const float* W; const float* bias;
    if (blockIdx.z == 0)      { x = q;   W = Wq; bias = bq; }
    else if (blockIdx.z == 1) { x = kk_; W = Wk; bias = bk; }
    else                      { x = v;   W = Wv; bias = bv; }

    const int t  = threadIdx.x;
    const int tx = t & 15;
    const int ty = t >> 4;
    const int i0 = blockIdx.y * 64;
    const int j0 = blockIdx.x * 64;

    float acc[4][4] = {};

    for (int k0 = 0; k0 < DDIM; k0 += 64) {
        __syncthreads();
#pragma unroll
        for (int i = 0; i < 4; ++i) {
            int idx = t + i * 256;
            int r = idx & 63, kq = idx >> 6;
            float4 xf = *(const float4*)&x[(size_t)(i0 + r) * DDIM + k0 + kq * 4];
            float4 wf = *(const float4*)&W[(size_t)(j0 + r) * DDIM + k0 + kq * 4];
            xsT[(4 * kq + 0) * 68 + r] = xf.x;
            xsT[(4 * kq + 1) * 68 + r] = xf.y;
            xsT[(4 * kq + 2) * 68 + r] = xf.z;
            xsT[(4 * kq + 3) * 68 + r] = xf.w;
            wsT[(4 * kq + 0) * 68 + r] = wf.x;
            wsT[(4 * kq + 1) * 68 + r] = wf.y;
            wsT[(4 * kq + 2) * 68 + r] = wf.z;
            wsT[(4 * kq + 3) * 68 + r] = wf.w;
        }
        __syncthreads();
#pragma unroll
        for (int k = 0; k < 64; ++k) {
            float4 a = *(const float4*)&xsT[k * 68 + ty * 4];
            float4 b = *(const float4*)&wsT[k * 68 + tx * 4];
            float av[4] = {a.x, a.y, a.z, a.w};
            float bv4[4] = {b.x, b.y, b.z, b.w};
#pragma unroll
            for (int i = 0; i < 4; ++i)
#pragma unroll
                for (int j = 0; j < 4; ++j)
                    acc[i][j] = fmaf(av[i], bv4[j], acc[i][j]);
        }
    }

#pragma unroll
    for (int j = 0; j < 4; ++j) {
        float bv = bias[j0 + tx * 4 + j];
#pragma unroll
        for (int i = 0; i < 4; ++i) {
            float val = acc[i][j] + bv;
            int row = i0 + ty * 4 + i;
            int col = j0 + tx * 4 + j;
            if (blockIdx.z == 0)
                eq[(size_t)row * DDIM + col] = __builtin_amdgcn_exp2f(val * CS);
            else if (blockIdx.z == 1)
                ekT[(size_t)col * MDIM + row] = __builtin_amdgcn_exp2f(val * CS);
            else
                vp[(size_t)row * DDIM + col] = val;
        }
    }
}

// ---------------- Score kernel: P[n,m] = mask ? exp(-2*acc) : 0 -------------
// acc = sum_d Ww[d] * rcp(1 + eq[n,d]*ekT[d,m]).
// 4 waves; wave w -> row n = by*4+w; lane -> 4 m's. ekT chunk [32 d][256 m]
// via global_load_lds width=16. Packed v_pk_fma_f32 for the full-rate fmas.
#define DCH 32
__global__ __launch_bounds__(256) void score_kernel(const float* __restrict__ eq,
                                                    const float* __restrict__ ekT,
                                                    const float* __restrict__ Ww,
                                                    const int* __restrict__ mask,
                                                    float* __restrict__ P)
{
    __shared__ __align__(16) float ks[DCH * 256];
    __shared__ float qs[4 * DCH];
    __shared__ float wws[DCH];

    const int t    = threadIdx.x;
    const int lane = t & 63;
    const int w    = t >> 6;
    const int m0   = blockIdx.x * 256;
    const int n    = blockIdx.y * 4 + w;

    v2f accA = {0.f, 0.f}, accB = {0.f, 0.f};
    const v2f one2 = {1.f, 1.f};

    for (int d0 = 0; d0 < DDIM; d0 += DCH) {
        __syncthreads();
#pragma unroll
        for (int i = 0; i < 8; ++i) {
            int r = w * 8 + i;                                   // wave-uniform
            load_lds16(ekT + (size_t)(d0 + r) * MDIM + m0 + lane * 4,
                       &ks[r * 256]);
        }
        if (t < 128) {
            int wq = t >> 5, dd = t & 31;
            qs[wq * DCH + dd] = eq[(size_t)(blockIdx.y * 4 + wq) * DDIM + d0 + dd];
        } else if (t < 160) {
            wws[t - 128] = Ww[d0 + t - 128];
        }
        __syncthreads();

#pragma unroll
        for (int dd = 0; dd < DCH; ++dd) {
            float eqv = qs[w * DCH + dd];
            float wv  = wws[dd];
            v2f eq2 = {eqv, eqv};
            v2f w2  = {wv, wv};
            float4 kv = *(const float4*)&ks[dd * 256 + lane * 4];
            v2f t01 = __builtin_elementwise_fma(eq2, (v2f){kv.x, kv.y}, one2);
            v2f t23 = __builtin_elementwise_fma(eq2, (v2f){kv.z, kv.w}, one2);
            v2f r01 = {__builtin_amdgcn_rcpf(t01.x), __builtin_amdgcn_rcpf(t01.y)};
            v2f r23 = {__builtin_amdgcn_rcpf(t23.x), __builtin_amdgcn_rcpf(t23.y)};
            accA = __builtin_elementwise_fma(w2, r01, accA);
            accB = __builtin_elementwise_fma(w2, r23, accB);
        }
    }

    const float C2 = -2.8853900817779268f;   // -2*log2(e)
    int4 mk = *(const int4*)&mask[(size_t)n * MDIM + m0 + lane * 4];
    float4 o;
    o.x = mk.x ? __builtin_amdgcn_exp2f(accA.x * C2) : 0.f;
    o.y = mk.y ? __builtin_amdgcn_exp2f(accA.y * C2) : 0.f;
    o.z = mk.z ? __builtin_amdgcn_exp2f(accB.x * C2) : 0.f;
    o.w = mk.w ? __builtin_amdgcn_exp2f(accB.y * C2) : 0.f;
    *(float4*)&P[(size_t)n * MDIM + m0 + lane * 4] = o;
}

// ---------------- Context GEMM (partial over m-range): C = P@vp -------------
// 64(n) x 64(d) tile, 4x4/thread, grid.z = m-split. psT transposed (VGPR
// staging, conflict-free); vs natural row-major via global_load_lds w=16.
__global__ __launch_bounds__(256) void ctx_gemm(const float* __restrict__ P,
                                                const float* __restrict__ vp,
                                                float* __restrict__ C,
                                                int mlen)
{
    __shared__ __align__(16) float psT[64 * 68];
    __shared__ __align__(16) float vs[64 * 64];
    const int t    = threadIdx.x;
    const int tx   = t & 15;
    const int ty   = t >> 4;
    const int lane = t & 63;
    const int w    = t >> 6;
    const int i0   = blockIdx.y * 64;
    const int d0   = blockIdx.x * 64;
    const int mb   = blockIdx.z * mlen;

    float acc[4][4] = {};

    for (int m0 = mb; m0 < mb + mlen; m0 += 64) {
        __syncthreads();
#pragma unroll
        for (int i = 0; i < 4; ++i) {
            int idx = t + i * 256;
            int r = idx & 63, kq = idx >> 6;
            float4 pf = *(const float4*)&P[(size_t)(i0 + r) * MDIM + m0 + kq * 4];
            psT[(4 * kq + 0) * 68 + r] = pf.x;
            psT[(4 * kq + 1) * 68 + r] = pf.y;
            psT[(4 * kq + 2) * 68 + r] = pf.z;
            psT[(4 * kq + 3) * 68 + r] = pf.w;
        }
#pragma unroll
        for (int j = 0; j < 4; ++j) {
            int rbase = w * 16 + j * 4;                          // wave-uniform
            load_lds16(vp + (size_t)(m0 + rbase + (lane >> 4)) * DDIM
                          + d0 + (lane & 15) * 4,
                       &vs[rbase * 64]);
        }
        __syncthreads();
#pragma unroll
        for (int k = 0; k < 64; ++k) {
            float4 a = *(const float4*)&psT[k * 68 + ty * 4];
            float4 b = *(const float4*)&vs[k * 64 + tx * 4];
            float av[4] = {a.x, a.y, a.z, a.w};
            float bv4[4] = {b.x, b.y, b.z, b.w};
#pragma unroll
            for (int i = 0; i < 4; ++i)
#pragma unroll
                for (int j = 0; j < 4; ++j)
                    acc[i][j] = fmaf(av[i], bv4[j], acc[i][j]);
        }
    }

    C += (size_t)blockIdx.z * (NROWS * DDIM);
#pragma unroll
    for (int i = 0; i < 4; ++i) {
        float4 o = {acc[i][0], acc[i][1], acc[i][2], acc[i][3]};
        *(float4*)&C[(size_t)(i0 + ty * 4 + i) * DDIM + d0 + tx * 4] = o;
    }
}

// ---------------- Combine: out[n,:] = (C0+C1)[n,:] / rowsum(P[n,:]) ---------
__global__ __launch_bounds__(256) void combine_kernel(const float* __restrict__ P,
                                                      const float* __restrict__ C0,
                                                      const float* __restrict__ C1,
                                                      int msplit,
                                                      float* __restrict__ out)
{
    const int t = threadIdx.x, lane = t & 63, w = t >> 6;
    const int n = blockIdx.x * 4 + w;

    const float4* prow = (const float4*)(P + (size_t)n * MDIM);
    float s = 0.f;
#pragma unroll
    for (int i = 0; i < 4; ++i) {
        float4 p = prow[lane + i * 64];
        s += (p.x + p.y) + (p.z + p.w);
    }
#pragma unroll
    for (int off = 32; off; off >>= 1) s += __shfl_xor(s, off);
    float inv = __builtin_amdgcn_rcpf(s);

#pragma unroll
    for (int i = 0; i < 2; ++i) {
        int c = lane * 4 + i * 256;
        float4 a = *(const float4*)&C0[(size_t)n * DDIM + c];
        if (msplit == 2) {
            float4 b = *(const float4*)&C1[(size_t)n * DDIM + c];
            a.x += b.x; a.y += b.y; a.z += b.z; a.w += b.w;
        }
        float4 o = {a.x * inv, a.y * inv, a.z * inv, a.w * inv};
        *(float4*)&out[(size_t)n * DDIM + c] = o;
    }
}

extern "C" void kernel_launch(void* const* d_in, const int* in_sizes, int n_in,
                              void* d_out, int out_size, void* d_ws, size_t ws_size,
                              hipStream_t stream)
{
    const float* q    = (const float*)d_in[0];
    const float* k    = (const float*)d_in[1];
    const float* v    = (const float*)d_in[2];
    const int*   mask = (const int*)d_in[3];
    const float* Wq   = (const float*)d_in[4];
    const float* bq   = (const float*)d_in[5];
    const float* Wk   = (const float*)d_in[6];
    const float* bk   = (const float*)d_in[7];
    const float* Wv   = (const float*)d_in[8];
    const float* bv   = (const float*)d_in[9];
    const float* Ww   = (const float*)d_in[10];
    // d_in[11] (bw) cancels under softmax.

    float* ws  = (float*)d_ws;
    float* eq  = ws;                         // 512K floats
    float* ekT = ws + 524288;                // 512K
    float* vp  = ws + 1048576;               // 512K
    float* P   = ws + 1572864;               // 1M
    float* C0  = ws + 2621440;               // 512K
    float* C1  = ws + 3145728;               // 512K
    float* out = (float*)d_out;

    const size_t need2 = (size_t)3670016 * 4;
    const int msplit = (ws_size >= need2) ? 2 : 1;
    const int mlen = MDIM / msplit;

    const float CS = 2.8853900817779268f;    // 2*log2(e)

    dim3 b256(256);
    proj_gemm<<<dim3(8, 16, 3), b256, 0, stream>>>(q, k, v, Wq, bq, Wk, bk,
                                                   Wv, bv, eq, ekT, vp, CS);
    score_kernel<<<dim3(4, 256), b256, 0, stream>>>(eq, ekT, Ww, mask, P);
    ctx_gemm<<<dim3(8, 16, msplit), b256, 0, stream>>>(P, vp, C0, mlen);
    combine_kernel<<<dim3(256), b256, 0, stream>>>(P, C0, C1, msplit, out);
}